// Round 1
// baseline (210.482 us; speedup 1.0000x reference)
//
#include <hip/hip_runtime.h>

// Problem constants (fixed by reference setup_inputs)
#define BB 32
#define DD 64
#define HH 16
#define TT 256
#define KK 512
#define NN (BB*HH*TT)          // 131072 tokens
#define HT (HH*TT)             // 4096
#define DHT (DD*HT)            // 262144
#define ZQ_SIZE (BB*DD*HH*TT)
#define COMMIT_OFF ZQ_SIZE
#define IDX_OFF (ZQ_SIZE+1)
#define PPL_OFF (IDX_OFF+NN)
#define USE_OFF (PPL_OFF+1)

// ws layout (float offsets):
#define CNT_OFF    0       // counts[512]
#define CPART_OFF  512     // per-wave commit partials[2048] (plain stores)
#define CDELTA_OFF 2560    // rescue commitment correction (float atomic)
#define RC_OFF     2561    // int rescue count
#define DONE_OFF   2562    // int gate counter for fused stats
#define RLIST_OFF  2564    // (token:int, dminA:float-bits) pairs, up to RMAX
#define RMAX       16384
// packed codebook, fragment-order: 32 ctl-tiles x [hi 2048B | lo 2048B] = 128 KB
// within a tile: code(0..15) * 128B, linear in d (uint4 = 8 consecutive-d bf16)
#define EB_OFF     36864   // 32768 floats

// rescue margin on the DOT scale: covers trunc-split err (~3e-5) + tag-pack quantum (~2.4e-4 x2)
#define MARGIN_A 1.5e-3f

using bf16x8 = __attribute__((ext_vector_type(8))) short;
using f32x4  = __attribute__((ext_vector_type(4))) float;

__device__ __forceinline__ bf16x8 bc(uint4 v) { return __builtin_bit_cast(bf16x8, v); }
__device__ __forceinline__ float pick4(float a0, float a1, float a2, float a3, int i) {
    float x = (i & 1) ? a1 : a0;
    float y = (i & 1) ? a3 : a2;
    return (i & 2) ? y : x;
}

// 32 blocks x 256: trunc-split bf16 codebook into fragment-contiguous layout;
// block 0 zeroes counts + cdelta + rc + done.
__global__ void vq_init(const float* __restrict__ emb, float* __restrict__ ws) {
    const int tid = threadIdx.x, blk = blockIdx.x;
    if (blk == 0) {
        ws[CNT_OFF + tid] = 0.0f;
        ws[CNT_OFF + 256 + tid] = 0.0f;
        if (tid == 0) {
            ws[CDELTA_OFF] = 0.0f;
            ((int*)ws)[RC_OFF] = 0;
            ((int*)ws)[DONE_OFF] = 0;
        }
    }
    const int k  = blk * 16 + (tid >> 4);
    const int d0 = (tid & 15) * 4;
    float4 v = *reinterpret_cast<const float4*>(emb + k * DD + d0);
    unsigned ux = __float_as_uint(v.x), uy = __float_as_uint(v.y);
    unsigned uz = __float_as_uint(v.z), uw = __float_as_uint(v.w);
    unsigned hx = ux & 0xFFFF0000u, hy = uy & 0xFFFF0000u;
    unsigned hz = uz & 0xFFFF0000u, hw = uw & 0xFFFF0000u;
    float lx = v.x - __uint_as_float(hx), ly = v.y - __uint_as_float(hy);
    float lz = v.z - __uint_as_float(hz), lw = v.w - __uint_as_float(hw);
    uint2 hi, lo;
    hi.x = (ux >> 16) | hy;
    hi.y = (uz >> 16) | hw;
    lo.x = (__float_as_uint(lx) >> 16) | (__float_as_uint(ly) & 0xFFFF0000u);
    lo.y = (__float_as_uint(lz) >> 16) | (__float_as_uint(lw) & 0xFFFF0000u);
    const int ctl = k >> 4, colc = k & 15;
    uint2* dst = reinterpret_cast<uint2*>(ws + EB_OFF);
    const int u2 = ctl * 512 + colc * 16 + (d0 >> 2);   // per-tile: 256 uint2 hi, 256 uint2 lo
    dst[u2]       = hi;
    dst[u2 + 256] = lo;
}

// Screen v2: barrier-free, LDS-free. 1 wave per block, 64 tokens/wave, 2048 blocks.
// B-fragments stream directly from the L1/L2-resident packed codebook with
// distance-2 register prefetch. Split-bf16 (truncation split) MFMA, 6 MFMA per
// 16x16 tile per K-half => exact-argmin screen with tiny rescue margin.
__global__ __launch_bounds__(64, 2) void vq_screen(
    const float* __restrict__ z_e, const float* __restrict__ emb,
    float* __restrict__ ws, float* __restrict__ out_zq, float* __restrict__ out_idx)
{
    const int lane = threadIdx.x;            // 0..63
    const int col  = lane & 15;
    const int q    = lane >> 4;
    const int W    = blockIdx.x;             // global wave id, 0..2047
    const int base_tok = W * 64;

    // ---- A fragments: 4 token-tiles x 2 k-frags, trunc-split hi/lo; + |z|^2 partials
    bf16x8 ah[4][2], al[4][2];
    float zp[4];
#pragma unroll
    for (int s = 0; s < 4; ++s) {
        zp[s] = 0.0f;
        const int n = base_tok + s * 16 + col;
        const size_t zoff = (size_t)(n >> 12) * DHT + (size_t)((n >> 8) & 15) * 256 + (size_t)(n & 255);
#pragma unroll
        for (int kf = 0; kf < 2; ++kf) {
            const int d0 = kf * 32 + q * 8;
            unsigned hu[4], lu[4];
#pragma unroll
            for (int jj = 0; jj < 4; ++jj) {
                float z0 = z_e[zoff + (size_t)(d0 + 2*jj + 0) * HT];
                float z1 = z_e[zoff + (size_t)(d0 + 2*jj + 1) * HT];
                zp[s] = fmaf(z0, z0, zp[s]);
                zp[s] = fmaf(z1, z1, zp[s]);
                unsigned u0 = __float_as_uint(z0), u1 = __float_as_uint(z1);
                unsigned h0 = u0 & 0xFFFF0000u,   h1 = u1 & 0xFFFF0000u;
                float l0 = z0 - __uint_as_float(h0);
                float l1 = z1 - __uint_as_float(h1);
                hu[jj] = (u0 >> 16) | h1;
                lu[jj] = (__float_as_uint(l0) >> 16) | (__float_as_uint(l1) & 0xFFFF0000u);
            }
            ah[s][kf] = bc(make_uint4(hu[0], hu[1], hu[2], hu[3]));
            al[s][kf] = bc(make_uint4(lu[0], lu[1], lu[2], lu[3]));
        }
    }
    // complete per-token |z|^2 (sum over the 4 q-lanes of each col)
#pragma unroll
    for (int s = 0; s < 4; ++s) {
        zp[s] += __shfl_xor(zp[s], 16, 64);
        zp[s] += __shfl_xor(zp[s], 32, 64);
    }

    // top-2 packed-max state (code id in low 9 mantissa bits)
    float m1[4][4], m2[4][4];
#pragma unroll
    for (int s = 0; s < 4; ++s)
#pragma unroll
        for (int r = 0; r < 4; ++r) { m1[s][r] = -3.4e38f; m2[s][r] = -3.4e38f; }

    unsigned ktag = (unsigned)col;

    // per-lane base into the packed codebook (uint4 units)
    const uint4* eb = reinterpret_cast<const uint4*>(ws + EB_OFF);
    const uint4* pb = eb + col * 8 + q;

    // distance-2 prefetch buffers (parity-indexed; full unroll keeps indices static)
    uint4 Bh0[2], Bh1[2], Bl0[2], Bl1[2];
    Bh0[0] = pb[0];   Bh1[0] = pb[4];   Bl0[0] = pb[128]; Bl1[0] = pb[132];
    Bh0[1] = pb[256]; Bh1[1] = pb[260]; Bl0[1] = pb[384]; Bl1[1] = pb[388];

#pragma unroll
    for (int ctl = 0; ctl < 32; ++ctl) {
        const int pr = ctl & 1;
        bf16x8 bh0 = bc(Bh0[pr]), bh1 = bc(Bh1[pr]);
        bf16x8 bl0 = bc(Bl0[pr]), bl1 = bc(Bl1[pr]);
        if (ctl < 30) {   // prefetch ctl+2 into the slot just consumed
            const uint4* pp = pb + (ctl + 2) * 256;
            Bh0[pr] = pp[0]; Bh1[pr] = pp[4]; Bl0[pr] = pp[128]; Bl1[pr] = pp[132];
        }
#pragma unroll
        for (int s = 0; s < 4; ++s) {
            f32x4 acc = {0.f, 0.f, 0.f, 0.f};
            acc = __builtin_amdgcn_mfma_f32_16x16x32_bf16(ah[s][0], bh0, acc, 0, 0, 0);
            acc = __builtin_amdgcn_mfma_f32_16x16x32_bf16(ah[s][1], bh1, acc, 0, 0, 0);
            acc = __builtin_amdgcn_mfma_f32_16x16x32_bf16(al[s][0], bh0, acc, 0, 0, 0);
            acc = __builtin_amdgcn_mfma_f32_16x16x32_bf16(al[s][1], bh1, acc, 0, 0, 0);
            acc = __builtin_amdgcn_mfma_f32_16x16x32_bf16(ah[s][0], bl0, acc, 0, 0, 0);
            acc = __builtin_amdgcn_mfma_f32_16x16x32_bf16(ah[s][1], bl1, acc, 0, 0, 0);
#pragma unroll
            for (int r = 0; r < 4; ++r) {
                float pk = __uint_as_float((__float_as_uint(acc[r]) & 0xFFFFFE00u) | ktag);
                m2[s][r] = __builtin_amdgcn_fmed3f(pk, m1[s][r], m2[s][r]);
                m1[s][r] = fmaxf(m1[s][r], pk);
            }
        }
        ktag += 16u;
    }

    // cross-lane top-2 merge: after this, ALL 16 col-lanes share identical m1/m2
#pragma unroll
    for (int msk = 1; msk <= 8; msk <<= 1) {
#pragma unroll
        for (int s = 0; s < 4; ++s)
#pragma unroll
            for (int r = 0; r < 4; ++r) {
                float o1 = __shfl_xor(m1[s][r], msk, 64);
                float o2 = __shfl_xor(m2[s][r], msk, 64);
                m2[s][r] = __builtin_amdgcn_fmed3f(m1[s][r], o1, fmaxf(m2[s][r], o2));
                m1[s][r] = fmaxf(m1[s][r], o1);
            }
    }

    // ---- per-lane writeout: lane handles token (s0 = col>>2, r0 = col&3, own q) ----
    const int s0 = col >> 2, r0 = col & 3;
    const int token = base_tok + s0 * 16 + q * 4 + r0;

    float m1v, m2v;
    {
        float a = pick4(m1[0][0], m1[0][1], m1[0][2], m1[0][3], r0);
        float b = pick4(m1[1][0], m1[1][1], m1[1][2], m1[1][3], r0);
        float c = pick4(m1[2][0], m1[2][1], m1[2][2], m1[2][3], r0);
        float d = pick4(m1[3][0], m1[3][1], m1[3][2], m1[3][3], r0);
        m1v = pick4(a, b, c, d, s0);
        a = pick4(m2[0][0], m2[0][1], m2[0][2], m2[0][3], r0);
        b = pick4(m2[1][0], m2[1][1], m2[1][2], m2[1][3], r0);
        c = pick4(m2[2][0], m2[2][1], m2[2][2], m2[2][3], r0);
        d = pick4(m2[3][0], m2[3][1], m2[3][2], m2[3][3], r0);
        m2v = pick4(a, b, c, d, s0);
    }
    // zsq of my token lives (for index s) on lane col==q*4+r0 (any q there)
    const int c0 = q * 4 + r0;
    float z0s = __shfl(zp[0], c0, 64);
    float z1s = __shfl(zp[1], c0, 64);
    float z2s = __shfl(zp[2], c0, 64);
    float z3s = __shfl(zp[3], c0, 64);
    const float zsqv = pick4(z0s, z1s, z2s, z3s, s0);

    const int k_sel = (int)(__float_as_uint(m1v) & 511u);
    const float dminA = fmaf(-2.0f, m1v, zsqv + 1.0f);   // ||z||^2 + 1 - 2*dot

    out_idx[token] = (float)k_sel;
    if (m1v - m2v < MARGIN_A) {
        int* rc = (int*)ws + RC_OFF;
        int pp = atomicAdd(rc, 1);
        if (pp < RMAX) {
            int* rl = (int*)ws + RLIST_OFF;
            rl[2 * pp] = token;
            rl[2 * pp + 1] = (int)__float_as_uint(dminA);
        }
    }
    // counts: direct per-token atomic (64-token blocks make a block-histogram useless)
    atomicAdd(ws + CNT_OFF + k_sel, 1.0f);

    // commitment: wave-reduce dminA -> one partial per wave (plain store)
    float csum = dminA;
#pragma unroll
    for (int off = 32; off > 0; off >>= 1) csum += __shfl_down(csum, off, 64);
    if (lane == 0) ws[CPART_OFF + W] = csum;

    // z_q: gather winner row (fp32, L2-hot) and write strided
    {
        const int b = token >> 12, h = (token >> 8) & 15, t = token & 255;
        const size_t zb = (size_t)b * DHT + (size_t)h * TT + (size_t)t;
        const float4* er = reinterpret_cast<const float4*>(emb + (size_t)k_sel * DD);
#pragma unroll
        for (int i = 0; i < 16; ++i) {
            float4 v = er[i];
            out_zq[zb + (size_t)(4*i+0) * HT] = v.x;
            out_zq[zb + (size_t)(4*i+1) * HT] = v.y;
            out_zq[zb + (size_t)(4*i+2) * HT] = v.z;
            out_zq[zb + (size_t)(4*i+3) * HT] = v.w;
        }
    }
}

// Rescue (exact fp32 rescan of ambiguous tokens) + fused stats via last-block gate.
__global__ void vq_rescue_stats(const float* __restrict__ z_e, const float* __restrict__ emb,
                                float* __restrict__ ws, float* __restrict__ out,
                                float* __restrict__ out_idx)
{
    __shared__ float lz[DD];
    __shared__ float sd[512];
    __shared__ int   si[512];
    __shared__ float s_com[512];
    __shared__ int   amlast;
    float* out_zq = out;
    const int tid = threadIdx.x;
    int cnt = ((const int*)ws)[RC_OFF];
    if (cnt > RMAX) cnt = RMAX;
    const int* rl = (const int*)ws + RLIST_OFF;

    for (int it = blockIdx.x; it < cnt; it += gridDim.x) {
        const int n = rl[2 * it];
        const float dminA = __uint_as_float((unsigned)rl[2 * it + 1]);
        const int b = n >> 12, h = (n >> 8) & 15;
        const size_t zoff = (size_t)b * DHT + (size_t)h * 256 + (size_t)(n & 255);
        __syncthreads();
        if (tid < DD) lz[tid] = z_e[zoff + (size_t)tid * HT];
        __syncthreads();
        const float4* er = reinterpret_cast<const float4*>(emb + (size_t)tid * DD);
        float a0 = 0.f, a1 = 0.f, a2 = 0.f, a3 = 0.f;
#pragma unroll
        for (int i = 0; i < 16; ++i) {
            float4 e4 = er[i];
            float d0 = lz[4*i+0] - e4.x; a0 = fmaf(d0, d0, a0);
            float d1 = lz[4*i+1] - e4.y; a1 = fmaf(d1, d1, a1);
            float d2 = lz[4*i+2] - e4.z; a2 = fmaf(d2, d2, a2);
            float d3 = lz[4*i+3] - e4.w; a3 = fmaf(d3, d3, a3);
        }
        sd[tid] = (a0 + a1) + (a2 + a3);
        si[tid] = tid;
        __syncthreads();
        for (int off = 256; off > 0; off >>= 1) {
            if (tid < off) {
                float d2 = sd[tid + off]; int j2 = si[tid + off];
                if (d2 < sd[tid] || (d2 == sd[tid] && j2 < si[tid])) { sd[tid] = d2; si[tid] = j2; }
            }
            __syncthreads();
        }
        const int   k_new = si[0];
        const float d_new = sd[0];
        const int   k_old = (int)out_idx[n];
        if (tid == 0) {
            atomicAdd(ws + CDELTA_OFF, d_new - dminA);   // exact commitment correction
            if (k_new != k_old) {
                out_idx[n] = (float)k_new;
                atomicAdd(ws + CNT_OFF + k_old, -1.0f);
                atomicAdd(ws + CNT_OFF + k_new,  1.0f);
            }
        }
        if (k_new != k_old && tid < DD)
            out_zq[zoff + (size_t)tid * HT] = emb[(size_t)k_new * DD + tid];
        __syncthreads();
    }

    // ---- gate: last block to finish runs the stats reduction ----
    __threadfence();
    if (tid == 0) {
        int d = atomicAdd((int*)ws + DONE_OFF, 1);
        amlast = (d == (int)gridDim.x - 1) ? 1 : 0;
    }
    __syncthreads();
    if (!amlast) return;

    // stats: counts/cdelta were atomically updated within this kernel -> agent-scope loads
    const int k = tid;
    const float c = __hip_atomic_load(ws + CNT_OFF + k, __ATOMIC_RELAXED, __HIP_MEMORY_SCOPE_AGENT);
    const float p = c * (1.0f / (float)NN);
    sd[k]    = p * logf(p + 1e-12f);
    si[k]    = (p > 0.0f) ? 1 : 0;
    s_com[k] = ws[CPART_OFF + k] + ws[CPART_OFF + 512 + k]
             + ws[CPART_OFF + 1024 + k] + ws[CPART_OFF + 1536 + k];
    __syncthreads();
    for (int off = 256; off > 0; off >>= 1) {
        if (k < off) {
            sd[k]    += sd[k + off];
            si[k]    += si[k + off];
            s_com[k] += s_com[k + off];
        }
        __syncthreads();
    }
    if (k == 0) {
        float cdelta = __hip_atomic_load(ws + CDELTA_OFF, __ATOMIC_RELAXED, __HIP_MEMORY_SCOPE_AGENT);
        out[COMMIT_OFF] = 0.25f * (s_com[0] + cdelta) / (float)ZQ_SIZE;
        out[PPL_OFF]    = expf(-sd[0]);
        out[USE_OFF]    = (float)si[0] / (float)KK;
    }
}

extern "C" void kernel_launch(void* const* d_in, const int* in_sizes, int n_in,
                              void* d_out, int out_size, void* d_ws, size_t ws_size,
                              hipStream_t stream) {
    const float* z_e = (const float*)d_in[0];
    const float* emb = (const float*)d_in[1];
    float* out = (float*)d_out;
    float* ws  = (float*)d_ws;

    float* out_idx = out + IDX_OFF;

    vq_init<<<32, 256, 0, stream>>>(emb, ws);
    vq_screen<<<2048, 64, 0, stream>>>(z_e, emb, ws, out, out_idx);
    vq_rescue_stats<<<256, 512, 0, stream>>>(z_e, emb, ws, out, out_idx);
}

// Round 2
// 209.388 us; speedup vs baseline: 1.0052x; 1.0052x over previous
//
#include <hip/hip_runtime.h>

// Problem constants (fixed by reference setup_inputs)
#define BB 32
#define DD 64
#define HH 16
#define TT 256
#define KK 512
#define NN (BB*HH*TT)          // 131072 tokens
#define HT (HH*TT)             // 4096
#define DHT (DD*HT)            // 262144
#define ZQ_SIZE (BB*DD*HH*TT)
#define COMMIT_OFF ZQ_SIZE
#define IDX_OFF (ZQ_SIZE+1)
#define PPL_OFF (IDX_OFF+NN)
#define USE_OFF (PPL_OFF+1)

// ws layout (float offsets):
#define CNT_OFF    0       // counts[512]
#define CPART_OFF  512     // per-wave commit partials[4096] (plain stores)
#define CDELTA_OFF 4608    // rescue commitment correction (float atomic)
#define RC_OFF     4609    // int rescue count
#define DONE_OFF   4610    // int gate counter for fused stats
#define RLIST_OFF  4612    // (token:int, dminA:float-bits) pairs, up to RMAX
#define RMAX       16384
#define EBH_OFF    37888   // 512x64 bf16 hi, code-major = 16384 floats
#define EBL_OFF    54272   // 512x64 bf16 lo, code-major = 16384 floats

// rescue margin on the DOT scale: covers trunc-split err (~1e-4) + tag-pack quantum (~5e-4 x2)
#define MARGIN_A 1.5e-3f

using bf16x8 = __attribute__((ext_vector_type(8))) short;
using f32x4  = __attribute__((ext_vector_type(4))) float;

__device__ __forceinline__ bf16x8 bc(uint4 v) { return __builtin_bit_cast(bf16x8, v); }
__device__ __forceinline__ float pick4(float a0, float a1, float a2, float a3, int i) {
    float x = (i & 1) ? a1 : a0;
    float y = (i & 1) ? a3 : a2;
    return (i & 2) ? y : x;
}

// 32 blocks x 256: trunc-split bf16 codebook (code-major, linear);
// block 0 zeroes counts + cdelta + rc + done.
__global__ void vq_init(const float* __restrict__ emb, float* __restrict__ ws) {
    const int tid = threadIdx.x, blk = blockIdx.x;
    if (blk == 0) {
        ws[CNT_OFF + tid] = 0.0f;
        ws[CNT_OFF + 256 + tid] = 0.0f;
        if (tid == 0) {
            ws[CDELTA_OFF] = 0.0f;
            ((int*)ws)[RC_OFF] = 0;
            ((int*)ws)[DONE_OFF] = 0;
        }
    }
    const int k  = blk * 16 + (tid >> 4);
    const int d0 = (tid & 15) * 4;
    float4 v = *reinterpret_cast<const float4*>(emb + k * DD + d0);
    unsigned ux = __float_as_uint(v.x), uy = __float_as_uint(v.y);
    unsigned uz = __float_as_uint(v.z), uw = __float_as_uint(v.w);
    unsigned hx = ux & 0xFFFF0000u, hy = uy & 0xFFFF0000u;
    unsigned hz = uz & 0xFFFF0000u, hw = uw & 0xFFFF0000u;
    float lx = v.x - __uint_as_float(hx), ly = v.y - __uint_as_float(hy);
    float lz = v.z - __uint_as_float(hz), lw = v.w - __uint_as_float(hw);
    uint2 hi, lo;
    hi.x = (ux >> 16) | hy;
    hi.y = (uz >> 16) | hw;
    lo.x = (__float_as_uint(lx) >> 16) | (__float_as_uint(ly) & 0xFFFF0000u);
    lo.y = (__float_as_uint(lz) >> 16) | (__float_as_uint(lw) & 0xFFFF0000u);
    reinterpret_cast<uint2*>(ws + EBH_OFF)[k * 16 + (d0 >> 2)] = hi;
    reinterpret_cast<uint2*>(ws + EBL_OFF)[k * 16 + (d0 >> 2)] = lo;
}

// Screen v3: LDS-staged like round-0 but tuned for 2x occupancy:
//   - 32 tokens/wave (2 s-tiles), 4096 waves, 1024 blocks x 256 threads
//   - 4 phases x 128 codes -> LDS 36,864 B/block -> 4 blocks/CU (16 waves/CU)
//   - __launch_bounds__(256,4) caps VGPR at 128 so registers don't cap occupancy
// Trunc-split bf16 MFMA (6 per 16x16 tile), packed top-2 with 9-bit code tag,
// register-prefetched B fragments, fused epilogue.
__global__ __launch_bounds__(256, 4) void vq_screen(
    const float* __restrict__ z_e, const float* __restrict__ emb,
    float* __restrict__ ws, float* __restrict__ out_zq, float* __restrict__ out_idx)
{
    __shared__ uint4 sh[2][1152];   // [hi/lo][128 codes * 9] = 36,864 B

    const int tid  = threadIdx.x;
    const int lane = tid & 63;
    const int col  = lane & 15;
    const int q    = lane >> 4;
    const int W    = (blockIdx.x << 2) | (tid >> 6);   // global wave id, 0..4095
    const int base_tok = W * 32;

    const uint4* ebh4 = reinterpret_cast<const uint4*>(ws + EBH_OFF);
    const uint4* ebl4 = reinterpret_cast<const uint4*>(ws + EBL_OFF);

    // ---- A fragments: 2 token-tiles x 2 k-frags, trunc-split hi/lo; + |z|^2 partials
    bf16x8 ah[2][2], al[2][2];
    float zp[2];
#pragma unroll
    for (int s = 0; s < 2; ++s) {
        zp[s] = 0.0f;
        const int n = base_tok + s * 16 + col;
        const size_t zoff = (size_t)(n >> 12) * DHT + (size_t)((n >> 8) & 15) * 256 + (size_t)(n & 255);
#pragma unroll
        for (int kf = 0; kf < 2; ++kf) {
            const int d0 = kf * 32 + q * 8;
            unsigned hu[4], lu[4];
#pragma unroll
            for (int jj = 0; jj < 4; ++jj) {
                float z0 = z_e[zoff + (size_t)(d0 + 2*jj + 0) * HT];
                float z1 = z_e[zoff + (size_t)(d0 + 2*jj + 1) * HT];
                zp[s] = fmaf(z0, z0, zp[s]);
                zp[s] = fmaf(z1, z1, zp[s]);
                unsigned u0 = __float_as_uint(z0), u1 = __float_as_uint(z1);
                unsigned h0 = u0 & 0xFFFF0000u,   h1 = u1 & 0xFFFF0000u;
                float l0 = z0 - __uint_as_float(h0);
                float l1 = z1 - __uint_as_float(h1);
                hu[jj] = (u0 >> 16) | h1;
                lu[jj] = (__float_as_uint(l0) >> 16) | (__float_as_uint(l1) & 0xFFFF0000u);
            }
            ah[s][kf] = bc(make_uint4(hu[0], hu[1], hu[2], hu[3]));
            al[s][kf] = bc(make_uint4(lu[0], lu[1], lu[2], lu[3]));
        }
    }
    // complete per-token |z|^2 (sum over the 4 q-lanes of each col)
#pragma unroll
    for (int s = 0; s < 2; ++s) {
        zp[s] += __shfl_xor(zp[s], 16, 64);
        zp[s] += __shfl_xor(zp[s], 32, 64);
    }

    // top-2 packed-max state (code id in low 9 mantissa bits)
    float m1[2][4], m2[2][4];
#pragma unroll
    for (int s = 0; s < 2; ++s)
#pragma unroll
        for (int r = 0; r < 4; ++r) { m1[s][r] = -3.4e38f; m2[s][r] = -3.4e38f; }

    unsigned ktag = (unsigned)col;
    const int idx0 = col * 9 + q;   // this lane's uint4 row base within a code-tile

#pragma unroll
    for (int p = 0; p < 4; ++p) {
        if (p) __syncthreads();   // previous phase's reads done before overwrite
#pragma unroll
        for (int j = 0; j < 4; ++j) {
            const int local = j * 256 + tid;
            const int c = local >> 3, jj = local & 7;
            sh[0][c * 9 + jj] = ebh4[p * 1024 + local];
            sh[1][c * 9 + jj] = ebl4[p * 1024 + local];
        }
        __syncthreads();

        // prologue loads for ctl=0
        uint4 nh0 = sh[0][idx0], nh1 = sh[0][idx0 + 4];
        uint4 nl0 = sh[1][idx0], nl1 = sh[1][idx0 + 4];

#pragma unroll
        for (int ctl = 0; ctl < 8; ++ctl) {
            bf16x8 bh0 = bc(nh0), bh1 = bc(nh1);
            bf16x8 bl0 = bc(nl0), bl1 = bc(nl1);
            if (ctl < 7) {   // prefetch next ctl BEFORE this ctl's MFMAs
                const int ni = idx0 + (ctl + 1) * 144;
                nh0 = sh[0][ni]; nh1 = sh[0][ni + 4];
                nl0 = sh[1][ni]; nl1 = sh[1][ni + 4];
            }
#pragma unroll
            for (int s = 0; s < 2; ++s) {
                f32x4 acc = {0.f, 0.f, 0.f, 0.f};
                acc = __builtin_amdgcn_mfma_f32_16x16x32_bf16(ah[s][0], bh0, acc, 0, 0, 0);
                acc = __builtin_amdgcn_mfma_f32_16x16x32_bf16(ah[s][1], bh1, acc, 0, 0, 0);
                acc = __builtin_amdgcn_mfma_f32_16x16x32_bf16(al[s][0], bh0, acc, 0, 0, 0);
                acc = __builtin_amdgcn_mfma_f32_16x16x32_bf16(al[s][1], bh1, acc, 0, 0, 0);
                acc = __builtin_amdgcn_mfma_f32_16x16x32_bf16(ah[s][0], bl0, acc, 0, 0, 0);
                acc = __builtin_amdgcn_mfma_f32_16x16x32_bf16(ah[s][1], bl1, acc, 0, 0, 0);
#pragma unroll
                for (int r = 0; r < 4; ++r) {
                    float pk = __uint_as_float((__float_as_uint(acc[r]) & 0xFFFFFE00u) | ktag);
                    m2[s][r] = __builtin_amdgcn_fmed3f(pk, m1[s][r], m2[s][r]);
                    m1[s][r] = fmaxf(m1[s][r], pk);
                }
            }
            ktag += 16u;
        }
    }

    // cross-lane top-2 merge: after this, ALL 16 col-lanes share identical m1/m2
#pragma unroll
    for (int msk = 1; msk <= 8; msk <<= 1) {
#pragma unroll
        for (int s = 0; s < 2; ++s)
#pragma unroll
            for (int r = 0; r < 4; ++r) {
                float o1 = __shfl_xor(m1[s][r], msk, 64);
                float o2 = __shfl_xor(m2[s][r], msk, 64);
                m2[s][r] = __builtin_amdgcn_fmed3f(m1[s][r], o1, fmaxf(m2[s][r], o2));
                m1[s][r] = fmaxf(m1[s][r], o1);
            }
    }

    // ---- writeout: 32 tokens, 2 lanes each. token = base + s0*16 + q*4 + r0,
    // s0=(col>>2)&1, r0=col&3; primary lanes col<8 do scalar ops.
    const int r0 = col & 3;
    const int s0 = (col >> 2) & 1;
    const int token = base_tok + s0 * 16 + q * 4 + r0;

    float m1v, m2v;
    {
        float a0 = pick4(m1[0][0], m1[0][1], m1[0][2], m1[0][3], r0);
        float a1 = pick4(m1[1][0], m1[1][1], m1[1][2], m1[1][3], r0);
        m1v = s0 ? a1 : a0;
        float b0 = pick4(m2[0][0], m2[0][1], m2[0][2], m2[0][3], r0);
        float b1 = pick4(m2[1][0], m2[1][1], m2[1][2], m2[1][3], r0);
        m2v = s0 ? b1 : b0;
    }
    // zsq of my token lives (for index s0) on lane c0 = q*4+r0 (its col == q*4+r0)
    const int c0 = q * 4 + r0;
    float z0s = __shfl(zp[0], c0, 64);
    float z1s = __shfl(zp[1], c0, 64);
    const float zsqv = s0 ? z1s : z0s;

    const int k_sel = (int)(__float_as_uint(m1v) & 511u);
    const float dminA = fmaf(-2.0f, m1v, zsqv + 1.0f);   // ||z||^2 + 1 - 2*dot

    if (col < 8) {
        out_idx[token] = (float)k_sel;
        if (m1v - m2v < MARGIN_A) {
            int* rc = (int*)ws + RC_OFF;
            int pp = atomicAdd(rc, 1);
            if (pp < RMAX) {
                int* rl = (int*)ws + RLIST_OFF;
                rl[2 * pp] = token;
                rl[2 * pp + 1] = (int)__float_as_uint(dminA);
            }
        }
        atomicAdd(ws + CNT_OFF + k_sel, 1.0f);
    }

    // commitment: every token counted twice across the wave -> store 0.5 * sum
    float csum = dminA;
#pragma unroll
    for (int off = 32; off > 0; off >>= 1) csum += __shfl_down(csum, off, 64);
    if (lane == 0) ws[CPART_OFF + W] = 0.5f * csum;

    // z_q: 2 lanes per token, 32 floats each (chunk = col>>3)
    {
        const int chunk = col >> 3;
        const int b = token >> 12, h = (token >> 8) & 15, t = token & 255;
        const size_t zb = (size_t)b * DHT + (size_t)h * TT + (size_t)t;
        const float4* er = reinterpret_cast<const float4*>(emb + (size_t)k_sel * DD) + chunk * 8;
#pragma unroll
        for (int i = 0; i < 8; ++i) {
            float4 v = er[i];
            const int d = chunk * 32 + 4 * i;
            out_zq[zb + (size_t)(d + 0) * HT] = v.x;
            out_zq[zb + (size_t)(d + 1) * HT] = v.y;
            out_zq[zb + (size_t)(d + 2) * HT] = v.z;
            out_zq[zb + (size_t)(d + 3) * HT] = v.w;
        }
    }
}

// Rescue (exact fp32 rescan of ambiguous tokens) + fused stats via last-block gate.
__global__ void vq_rescue_stats(const float* __restrict__ z_e, const float* __restrict__ emb,
                                float* __restrict__ ws, float* __restrict__ out,
                                float* __restrict__ out_idx)
{
    __shared__ float lz[DD];
    __shared__ float sd[512];
    __shared__ int   si[512];
    __shared__ float s_com[512];
    __shared__ int   amlast;
    float* out_zq = out;
    const int tid = threadIdx.x;
    int cnt = ((const int*)ws)[RC_OFF];
    if (cnt > RMAX) cnt = RMAX;
    const int* rl = (const int*)ws + RLIST_OFF;

    for (int it = blockIdx.x; it < cnt; it += gridDim.x) {
        const int n = rl[2 * it];
        const float dminA = __uint_as_float((unsigned)rl[2 * it + 1]);
        const int b = n >> 12, h = (n >> 8) & 15;
        const size_t zoff = (size_t)b * DHT + (size_t)h * 256 + (size_t)(n & 255);
        __syncthreads();
        if (tid < DD) lz[tid] = z_e[zoff + (size_t)tid * HT];
        __syncthreads();
        const float4* er = reinterpret_cast<const float4*>(emb + (size_t)tid * DD);
        float a0 = 0.f, a1 = 0.f, a2 = 0.f, a3 = 0.f;
#pragma unroll
        for (int i = 0; i < 16; ++i) {
            float4 e4 = er[i];
            float d0 = lz[4*i+0] - e4.x; a0 = fmaf(d0, d0, a0);
            float d1 = lz[4*i+1] - e4.y; a1 = fmaf(d1, d1, a1);
            float d2 = lz[4*i+2] - e4.z; a2 = fmaf(d2, d2, a2);
            float d3 = lz[4*i+3] - e4.w; a3 = fmaf(d3, d3, a3);
        }
        sd[tid] = (a0 + a1) + (a2 + a3);
        si[tid] = tid;
        __syncthreads();
        for (int off = 256; off > 0; off >>= 1) {
            if (tid < off) {
                float d2 = sd[tid + off]; int j2 = si[tid + off];
                if (d2 < sd[tid] || (d2 == sd[tid] && j2 < si[tid])) { sd[tid] = d2; si[tid] = j2; }
            }
            __syncthreads();
        }
        const int   k_new = si[0];
        const float d_new = sd[0];
        const int   k_old = (int)out_idx[n];
        if (tid == 0) {
            atomicAdd(ws + CDELTA_OFF, d_new - dminA);   // exact commitment correction
            if (k_new != k_old) {
                out_idx[n] = (float)k_new;
                atomicAdd(ws + CNT_OFF + k_old, -1.0f);
                atomicAdd(ws + CNT_OFF + k_new,  1.0f);
            }
        }
        if (k_new != k_old && tid < DD)
            out_zq[zoff + (size_t)tid * HT] = emb[(size_t)k_new * DD + tid];
        __syncthreads();
    }

    // ---- gate: last block to finish runs the stats reduction ----
    __threadfence();
    if (tid == 0) {
        int d = atomicAdd((int*)ws + DONE_OFF, 1);
        amlast = (d == (int)gridDim.x - 1) ? 1 : 0;
    }
    __syncthreads();
    if (!amlast) return;

    // stats: counts/cdelta were atomically updated within this kernel -> agent-scope loads
    const int k = tid;
    const float c = __hip_atomic_load(ws + CNT_OFF + k, __ATOMIC_RELAXED, __HIP_MEMORY_SCOPE_AGENT);
    const float p = c * (1.0f / (float)NN);
    sd[k]    = p * logf(p + 1e-12f);
    si[k]    = (p > 0.0f) ? 1 : 0;
    float cs = 0.0f;
#pragma unroll
    for (int i = 0; i < 8; ++i) cs += ws[CPART_OFF + k + 512 * i];
    s_com[k] = cs;
    __syncthreads();
    for (int off = 256; off > 0; off >>= 1) {
        if (k < off) {
            sd[k]    += sd[k + off];
            si[k]    += si[k + off];
            s_com[k] += s_com[k + off];
        }
        __syncthreads();
    }
    if (k == 0) {
        float cdelta = __hip_atomic_load(ws + CDELTA_OFF, __ATOMIC_RELAXED, __HIP_MEMORY_SCOPE_AGENT);
        out[COMMIT_OFF] = 0.25f * (s_com[0] + cdelta) / (float)ZQ_SIZE;
        out[PPL_OFF]    = expf(-sd[0]);
        out[USE_OFF]    = (float)si[0] / (float)KK;
    }
}

extern "C" void kernel_launch(void* const* d_in, const int* in_sizes, int n_in,
                              void* d_out, int out_size, void* d_ws, size_t ws_size,
                              hipStream_t stream) {
    const float* z_e = (const float*)d_in[0];
    const float* emb = (const float*)d_in[1];
    float* out = (float*)d_out;
    float* ws  = (float*)d_ws;

    float* out_idx = out + IDX_OFF;

    vq_init<<<32, 256, 0, stream>>>(emb, ws);
    vq_screen<<<1024, 256, 0, stream>>>(z_e, emb, ws, out, out_idx);
    vq_rescue_stats<<<256, 512, 0, stream>>>(z_e, emb, ws, out, out_idx);
}